// Round 8
// baseline (220.822 us; speedup 1.0000x reference)
//
#include <hip/hip_runtime.h>
#include <hip/hip_bf16.h>
#include <math.h>

#define N_POINTS 1000000
#define N_GRIDS  16
#define LOG2_T   19
#define TABLE_MASK ((1u << LOG2_T) - 1u)
#define NBLOCKS  ((N_POINTS + 255) / 256)
#define CONV_BLOCKS 4096
#define FUSED_BLOCKS 2048          // multiple of 8; 8 groups -> 8 XCDs
#define TAILB_BLOCKS 4096
#define N_ENTRIES (N_GRIDS << LOG2_T)   // 8.4M bf16x2 entries
#define NCELL_AX 32                // Morton bucket grid 32^3
#define N_CELLS  (NCELL_AX * NCELL_AX * NCELL_AX)   // 32768

struct ResArr { float r[N_GRIDS]; };
struct Task    { int g, lo, hi; };         // lo/hi in 1/256ths of cnt
struct TaskTab { Task t[8][6]; int n[8]; };

__device__ __forceinline__ unsigned pack_bf16x2(float a, float b)
{
    __hip_bfloat16 ha = __float2bfloat16(a);
    __hip_bfloat16 hb = __float2bfloat16(b);
    unsigned short ua = *(unsigned short*)&ha;
    unsigned short ub = *(unsigned short*)&hb;
    return (unsigned)ua | ((unsigned)ub << 16);
}

__device__ __forceinline__ float2 unpack_bf16x2(unsigned v)
{
    unsigned lo = (v & 0xffffu) << 16;
    unsigned hi = v & 0xffff0000u;
    return make_float2(__uint_as_float(lo), __uint_as_float(hi));
}

// 5-bit -> every-3rd-bit expansion for Morton codes
__device__ __forceinline__ unsigned expand_bits(unsigned v)
{
    v &= 0x3ffu;
    v = (v | (v << 16)) & 0x30000FFu;
    v = (v | (v << 8))  & 0x300F00Fu;
    v = (v | (v << 4))  & 0x30C30C3u;
    v = (v | (v << 2))  & 0x9249249u;
    return v;
}

__device__ __forceinline__ int morton_cell(float x0, float x1, float x2)
{
    int cx = (int)floorf((x0 + 1.f) * 16.f);
    int cy = (int)floorf((x1 + 1.f) * 16.f);
    int cz = (int)floorf((x2 + 1.f) * 16.f);
    cx = min(NCELL_AX - 1, max(0, cx));
    cy = min(NCELL_AX - 1, max(0, cy));
    cz = min(NCELL_AX - 1, max(0, cz));
    return (int)((expand_bits((unsigned)cx) << 2) |
                 (expand_bits((unsigned)cy) << 1) |
                  expand_bits((unsigned)cz));
}

// R2-exact gather (measured best): 8 clustered 4 B loads, then fma phase.
// R7's paired-uint2 variant regressed (115 vs 110 us) -> reverted.
__device__ __forceinline__ void gather_level_bf16(
    float x0, float x1, float x2, float r,
    const unsigned* __restrict__ tbl, float& c0, float& c1)
{
    // match reference: (x + 1.0) * 0.5 * r, left-to-right fp32
    const float xn0 = (x0 + 1.0f) * 0.5f * r;
    const float xn1 = (x1 + 1.0f) * 0.5f * r;
    const float xn2 = (x2 + 1.0f) * 0.5f * r;
    const float f0 = floorf(xn0), f1 = floorf(xn1), f2 = floorf(xn2);
    const unsigned v0 = (unsigned)(int)f0;
    const unsigned v1 = (unsigned)(int)f1;
    const unsigned v2 = (unsigned)(int)f2;
    const float w0 = xn0 - f0, w1 = xn1 - f1, w2 = xn2 - f2;

    unsigned fv[8];
    #pragma unroll
    for (int k = 0; k < 8; ++k) {
        const unsigned vx = v0 + ((k >> 2) & 1);
        const unsigned vy = v1 + ((k >> 1) & 1);
        const unsigned vz = v2 + (k & 1);
        unsigned h = vx ^ (vy * 2654435761u) ^ (vz * 805459861u);
        fv[k] = tbl[h & TABLE_MASK];
    }
    c0 = 0.f; c1 = 0.f;
    #pragma unroll
    for (int k = 0; k < 8; ++k) {
        const float wgt = ((k & 4) ? w0 : 1.0f - w0) *
                          ((k & 2) ? w1 : 1.0f - w1) *
                          ((k & 1) ? w2 : 1.0f - w2);
        const float2 f = unpack_bf16x2(fv[k]);
        c0 += wgt * f.x;
        c1 += wgt * f.y;
    }
}

// ---- pass 0: fat kernel = Morton histogram || table fp32->bf16x2 convert ---
__global__ __launch_bounds__(256)
void hist_conv_kernel(const float* __restrict__ x, int* __restrict__ rank,
                      unsigned* __restrict__ hist,
                      const float* __restrict__ tables,
                      unsigned* __restrict__ tb)
{
    if (blockIdx.x < NBLOCKS) {
        const int p = blockIdx.x * 256 + threadIdx.x;
        if (p >= N_POINTS) return;
        const float x0 = x[3 * p], x1 = x[3 * p + 1], x2 = x[3 * p + 2];
        const bool inbox = (x0 >= -1.f) & (x0 <= 1.f) &
                           (x1 >= -1.f) & (x1 <= 1.f) &
                           (x2 >= -1.f) & (x2 <= 1.f);
        if (inbox) {
            const int cell = morton_cell(x0, x1, x2);
            atomicAdd(&hist[cell], 1u);
            rank[p] = cell;
        } else {
            rank[p] = -1;
        }
    } else {
        const unsigned nthr = CONV_BLOCKS * 256;
        for (unsigned e4 = (blockIdx.x - NBLOCKS) * 256 + threadIdx.x;
             e4 < (N_ENTRIES / 4); e4 += nthr) {
            const float4 a = ((const float4*)tables)[2 * e4];
            const float4 b = ((const float4*)tables)[2 * e4 + 1];
            uint4 o;
            o.x = pack_bf16x2(a.x, a.y);
            o.y = pack_bf16x2(a.z, a.w);
            o.z = pack_bf16x2(b.x, b.y);
            o.w = pack_bf16x2(b.z, b.w);
            ((uint4*)tb)[e4] = o;
        }
    }
}

// ---- pass 0.5: single-block exclusive scan (vectorized uint4 I/O) ----------
__global__ __launch_bounds__(1024)
void scan_kernel(unsigned* __restrict__ hist, unsigned* __restrict__ counter)
{
    __shared__ unsigned partial[1024];
    const int tid = threadIdx.x;
    uint4* __restrict__ hp = (uint4*)hist + tid * 8;   // 32 cells = 8 uint4
    uint4 vv[8];
    unsigned s = 0;
    #pragma unroll
    for (int i = 0; i < 8; ++i) {
        vv[i] = hp[i];
        s += vv[i].x + vv[i].y + vv[i].z + vv[i].w;
    }
    partial[tid] = s;
    __syncthreads();
    for (int off = 1; off < 1024; off <<= 1) {
        unsigned t = (tid >= off) ? partial[tid - off] : 0u;
        __syncthreads();
        partial[tid] += t;
        __syncthreads();
    }
    if (tid == 1023) counter[0] = partial[1023];
    unsigned run = partial[tid] - s;           // exclusive prefix
    #pragma unroll
    for (int i = 0; i < 8; ++i) {
        uint4 o;
        o.x = run; run += vv[i].x;
        o.y = run; run += vv[i].y;
        o.z = run; run += vv[i].z;
        o.w = run; run += vv[i].w;
        hp[i] = o;
    }
}

// ---- pass 0.75: scatter points into Morton-sorted order --------------------
// Stores the ORIGINAL point index in xw.w (bit-cast) for the tail.
__global__ __launch_bounds__(256)
void scatter_kernel(const float* __restrict__ x, int* __restrict__ rank,
                    float4* __restrict__ xw, unsigned* __restrict__ hist)
{
    const int p = blockIdx.x * 256 + threadIdx.x;
    if (p >= N_POINTS) return;
    const int cell = rank[p];
    if (cell < 0) return;                      // rank stays -1
    const unsigned rk = atomicAdd(&hist[cell], 1u);
    rank[p] = (int)rk;
    xw[rk] = make_float4(x[3 * p], x[3 * p + 1], x[3 * p + 2],
                         __int_as_float(p));
}

// ---- pass 1: miss-weighted-balanced task schedule, task-major loop ----------
// Model (fits R2/R4/R5/R6/R7): time ~ busiest XCD's (L2 hit-requests +
// ~2x miss-fills). R2's makespan = group(7,8) at 2.0 heavy-units; full
// splitting (R5) balances requests but ~triples misses via table
// replication. Minimum-replication rebalance:
//   G0..G6: one whole heavy level (7..13) each; G0 also L4; L14+L15 sliced
//   across G0..G6 only (+24 MB fetch). G7: all remaining light levels.
// Loads: G0-6 ~1.31, G7 ~1.38 (vs 2.0). Task-MAJOR loop keeps all blocks
// of a group on the same task -> one table hot per XCD (R4's failure fixed).
__global__ __launch_bounds__(256)
void fused_levels_kernel(const float4* __restrict__ xw,
                         const unsigned* __restrict__ counter,
                         const unsigned* __restrict__ tb,
                         unsigned* __restrict__ ws2, ResArr res, TaskTab tt)
{
    const unsigned k    = blockIdx.x & 7;
    const unsigned bix  = blockIdx.x >> 3;
    const unsigned nbx  = gridDim.x >> 3;
    const unsigned cnt  = *counter;

    #pragma unroll 1
    for (int tix = 0; tix < tt.n[k]; ++tix) {
        const int g = tt.t[k][tix].g;
        const unsigned lo =
            (unsigned)(((unsigned long long)tt.t[k][tix].lo * cnt) >> 8);
        const unsigned hi =
            (unsigned)(((unsigned long long)tt.t[k][tix].hi * cnt) >> 8);
        const unsigned len = hi - lo;
        if (!len) continue;
        const unsigned per = (len + nbx - 1) / nbx;
        const unsigned s0  = lo + bix * per;
        const unsigned s1  = min(hi, s0 + per);

        const float r = res.r[g];
        const unsigned* __restrict__ tbl = tb + ((size_t)g << LOG2_T);
        unsigned* __restrict__ wrow = ws2 + (size_t)g * N_POINTS;
        for (unsigned i = s0 + threadIdx.x; i < s1; i += 256) {
            const float4 v = xw[i];
            float c0, c1;
            gather_level_bf16(v.x, v.y, v.z, r, tbl, c0, c1);
            wrow[i] = pack_bf16x2(c0, c1);
        }
    }
}

// ---- pass 2: tail -----------------------------------------------------------
// Part A: zero-fill rows of out-of-box points (orig order, predicated).
// Part B: iterate SORTED index -> ws2 reads; 8 threads/point write the
// 128 B output row contiguously (random writes are fire-and-forget).
__global__ __launch_bounds__(256)
void tail_kernel(const int* __restrict__ rank, const float4* __restrict__ xw,
                 const unsigned* __restrict__ counter,
                 const unsigned* __restrict__ ws2, float* __restrict__ out)
{
    const int t = threadIdx.x;
    if (blockIdx.x < NBLOCKS) {
        const int P0 = blockIdx.x * 256;
        float4* __restrict__ out4 = (float4*)out + (size_t)P0 * 8;
        const float4 z = make_float4(0.f, 0.f, 0.f, 0.f);
        #pragma unroll
        for (int i = 0; i < 8; ++i) {
            const int j  = i * 256 + t;
            const int pp = P0 + (j >> 3);
            if (pp < N_POINTS && rank[pp] < 0) out4[j] = z;
        }
    } else {
        const unsigned cnt = *counter;
        const unsigned tot = cnt * 8u;
        const unsigned bix = blockIdx.x - NBLOCKS;
        for (unsigned tg = bix * 256 + t; tg < tot; tg += TAILB_BLOCKS * 256) {
            const unsigned i = tg >> 3, q = tg & 7;
            const unsigned a = ws2[(size_t)(2 * q) * N_POINTS + i];
            const unsigned b = ws2[(size_t)(2 * q + 1) * N_POINTS + i];
            const int p = __float_as_int(xw[i].w);
            const float2 fa = unpack_bf16x2(a);
            const float2 fb = unpack_bf16x2(b);
            ((float4*)out)[(size_t)p * 8 + q] =
                make_float4(fa.x, fa.y, fb.x, fb.y);
        }
    }
}

// ---- fallback (ws too small): R1-style monolithic kernel (fp32 tables) -----
__device__ __forceinline__ void gather_level_f32(
    float x0, float x1, float x2, float r,
    const float2* __restrict__ tbl, float& c0, float& c1)
{
    const float xn0 = (x0 + 1.0f) * 0.5f * r;
    const float xn1 = (x1 + 1.0f) * 0.5f * r;
    const float xn2 = (x2 + 1.0f) * 0.5f * r;
    const float f0 = floorf(xn0), f1 = floorf(xn1), f2 = floorf(xn2);
    const unsigned v0 = (unsigned)(int)f0;
    const unsigned v1 = (unsigned)(int)f1;
    const unsigned v2 = (unsigned)(int)f2;
    const float w0 = xn0 - f0, w1 = xn1 - f1, w2 = xn2 - f2;
    c0 = 0.f; c1 = 0.f;
    #pragma unroll
    for (int k = 0; k < 8; ++k) {
        const unsigned vx = v0 + ((k >> 2) & 1);
        const unsigned vy = v1 + ((k >> 1) & 1);
        const unsigned vz = v2 + (k & 1);
        unsigned h = (vx * 1u) ^ (vy * 2654435761u) ^ (vz * 805459861u);
        h &= TABLE_MASK;
        const float wgt = ((k & 4) ? w0 : 1.0f - w0) *
                          ((k & 2) ? w1 : 1.0f - w1) *
                          ((k & 1) ? w2 : 1.0f - w2);
        const float2 f = tbl[h];
        c0 += wgt * f.x;
        c1 += wgt * f.y;
    }
}

__global__ __launch_bounds__(256)
void mono_kernel(const float* __restrict__ x, const float* __restrict__ tables,
                 float* __restrict__ out, ResArr res)
{
    int idx = blockIdx.x * blockDim.x + threadIdx.x;
    if (idx >= N_POINTS * N_GRIDS) return;
    int b = idx >> 4, g = idx & 15;
    float x0 = x[b * 3], x1 = x[b * 3 + 1], x2 = x[b * 3 + 2];
    bool inbox = (x0 >= -1.f) & (x0 <= 1.f) & (x1 >= -1.f) & (x1 <= 1.f) &
                 (x2 >= -1.f) & (x2 <= 1.f);
    float c0 = 0.f, c1 = 0.f;
    if (inbox) {
        const float2* tbl = (const float2*)tables + ((size_t)g << LOG2_T);
        gather_level_f32(x0, x1, x2, res.r[g], tbl, c0, c1);
    }
    ((float2*)out)[(size_t)b * N_GRIDS + g] = make_float2(c0, c1);
}

extern "C" void kernel_launch(void* const* d_in, const int* in_sizes, int n_in,
                              void* d_out, int out_size, void* d_ws, size_t ws_size,
                              hipStream_t stream)
{
    const float* x      = (const float*)d_in[0];
    const float* tables = (const float*)d_in[1];
    float* out          = (float*)d_out;

    ResArr res;
    double pls = exp((log(2048.0) - log(16.0)) / 15.0);
    for (int i = 0; i < N_GRIDS; ++i)
        res.r[i] = (float)floor(16.0 * pow(pls, (double)i));

    // ---- build the miss-weighted-balanced task table ----
    TaskTab tt;
    for (int k = 0; k < 8; ++k) tt.n[k] = 0;
    auto add = [&](int grp, int g, int lo, int hi) {
        tt.t[grp][tt.n[grp]].g  = g;
        tt.t[grp][tt.n[grp]].lo = lo;
        tt.t[grp][tt.n[grp]].hi = hi;
        tt.n[grp]++;
    };
    // G0..G6: one whole heavy level each (L7..L13); G0 also hosts L4
    for (int k = 0; k < 7; ++k) add(k, 7 + k, 0, 256);
    add(0, 4, 0, 256);
    // L14+L15 as virtual range [0,512), sliced across G0..G6
    // (G0 smaller share to offset its L4; G1-6 ~79/256 each)
    const int cuts[8] = {0, 36, 116, 195, 274, 353, 432, 512};
    for (int k = 0; k < 7; ++k) {
        int a = cuts[k], b = cuts[k + 1];
        if (a < 256 && b > 0) {            // overlap with L14
            int lo = a, hi = b < 256 ? b : 256;
            if (lo < hi) add(k, 14, lo, hi);
        }
        if (b > 256) {                     // overlap with L15
            int lo = a > 256 ? a - 256 : 0, hi = b - 256;
            if (lo < hi) add(k, 15, lo, hi);
        }
    }
    // G7: all remaining light levels, descending cost
    add(7, 6, 0, 256);
    add(7, 5, 0, 256);
    add(7, 3, 0, 256);
    add(7, 2, 0, 256);
    add(7, 1, 0, 256);
    add(7, 0, 0, 256);

    // ws layout:
    // [counter 256B][hist 128KB][rank 4MB][xw 16MB][ws2 64MB][tb 33.6MB]
    const size_t off_hist = 256;
    const size_t off_rank = off_hist + (size_t)N_CELLS * 4;
    const size_t off_xw   = off_rank + (size_t)N_POINTS * 4;
    const size_t off_ws2  = off_xw + (size_t)N_POINTS * 16;
    const size_t off_tb   = off_ws2 + (size_t)N_GRIDS * N_POINTS * 4;
    const size_t ws_needed = off_tb + (size_t)N_ENTRIES * 4;

    if (ws_size < ws_needed) {
        int total = N_POINTS * N_GRIDS;
        mono_kernel<<<(total + 255) / 256, 256, 0, stream>>>(x, tables, out, res);
        return;
    }

    char* w = (char*)d_ws;
    unsigned* counter = (unsigned*)w;
    unsigned* hist    = (unsigned*)(w + off_hist);
    int*      rank    = (int*)(w + off_rank);
    float4*   xw      = (float4*)(w + off_xw);
    unsigned* ws2     = (unsigned*)(w + off_ws2);
    unsigned* tb      = (unsigned*)(w + off_tb);

    (void)hipMemsetAsync(w, 0, off_rank, stream);   // counter + hist
    hist_conv_kernel<<<NBLOCKS + CONV_BLOCKS, 256, 0, stream>>>(
        x, rank, hist, tables, tb);
    scan_kernel<<<1, 1024, 0, stream>>>(hist, counter);
    scatter_kernel<<<NBLOCKS, 256, 0, stream>>>(x, rank, xw, hist);
    fused_levels_kernel<<<FUSED_BLOCKS, 256, 0, stream>>>(xw, counter, tb,
                                                          ws2, res, tt);
    tail_kernel<<<NBLOCKS + TAILB_BLOCKS, 256, 0, stream>>>(rank, xw, counter,
                                                            ws2, out);
}

// Round 9
// 208.082 us; speedup vs baseline: 1.0612x; 1.0612x over previous
//
#include <hip/hip_runtime.h>
#include <hip/hip_bf16.h>
#include <math.h>

#define N_POINTS 1000000
#define N_GRIDS  16
#define LOG2_T   19
#define TABLE_MASK ((1u << LOG2_T) - 1u)
#define NBLOCKS  ((N_POINTS + 255) / 256)
#define CONV_BLOCKS 4096
#define FUSED_BLOCKS 2048          // multiple of 8; 8 groups -> 8 XCDs
#define TAILB_BLOCKS 4096
#define N_ENTRIES (N_GRIDS << LOG2_T)   // 8.4M bf16x2 entries
#define NCELL_AX 32                // Morton bucket grid 32^3
#define N_CELLS  (NCELL_AX * NCELL_AX * NCELL_AX)   // 32768

struct ResArr { float r[N_GRIDS]; };
struct Task    { int g, lo, hi; };         // lo/hi in 1/256ths of cnt
struct TaskTab { Task t[8][6]; int n[8]; };

__device__ __forceinline__ unsigned pack_bf16x2(float a, float b)
{
    __hip_bfloat16 ha = __float2bfloat16(a);
    __hip_bfloat16 hb = __float2bfloat16(b);
    unsigned short ua = *(unsigned short*)&ha;
    unsigned short ub = *(unsigned short*)&hb;
    return (unsigned)ua | ((unsigned)ub << 16);
}

__device__ __forceinline__ float2 unpack_bf16x2(unsigned v)
{
    unsigned lo = (v & 0xffffu) << 16;
    unsigned hi = v & 0xffff0000u;
    return make_float2(__uint_as_float(lo), __uint_as_float(hi));
}

// 5-bit -> every-3rd-bit expansion for Morton codes
__device__ __forceinline__ unsigned expand_bits(unsigned v)
{
    v &= 0x3ffu;
    v = (v | (v << 16)) & 0x30000FFu;
    v = (v | (v << 8))  & 0x300F00Fu;
    v = (v | (v << 4))  & 0x30C30C3u;
    v = (v | (v << 2))  & 0x9249249u;
    return v;
}

__device__ __forceinline__ int morton_cell(float x0, float x1, float x2)
{
    int cx = (int)floorf((x0 + 1.f) * 16.f);
    int cy = (int)floorf((x1 + 1.f) * 16.f);
    int cz = (int)floorf((x2 + 1.f) * 16.f);
    cx = min(NCELL_AX - 1, max(0, cx));
    cy = min(NCELL_AX - 1, max(0, cy));
    cz = min(NCELL_AX - 1, max(0, cz));
    return (int)((expand_bits((unsigned)cx) << 2) |
                 (expand_bits((unsigned)cy) << 1) |
                  expand_bits((unsigned)cz));
}

// R2-exact gather (measured best): 8 clustered 4 B loads, then fma phase.
__device__ __forceinline__ void gather_level_bf16(
    float x0, float x1, float x2, float r,
    const unsigned* __restrict__ tbl, float& c0, float& c1)
{
    // match reference: (x + 1.0) * 0.5 * r, left-to-right fp32
    const float xn0 = (x0 + 1.0f) * 0.5f * r;
    const float xn1 = (x1 + 1.0f) * 0.5f * r;
    const float xn2 = (x2 + 1.0f) * 0.5f * r;
    const float f0 = floorf(xn0), f1 = floorf(xn1), f2 = floorf(xn2);
    const unsigned v0 = (unsigned)(int)f0;
    const unsigned v1 = (unsigned)(int)f1;
    const unsigned v2 = (unsigned)(int)f2;
    const float w0 = xn0 - f0, w1 = xn1 - f1, w2 = xn2 - f2;

    unsigned fv[8];
    #pragma unroll
    for (int k = 0; k < 8; ++k) {
        const unsigned vx = v0 + ((k >> 2) & 1);
        const unsigned vy = v1 + ((k >> 1) & 1);
        const unsigned vz = v2 + (k & 1);
        unsigned h = vx ^ (vy * 2654435761u) ^ (vz * 805459861u);
        fv[k] = tbl[h & TABLE_MASK];
    }
    c0 = 0.f; c1 = 0.f;
    #pragma unroll
    for (int k = 0; k < 8; ++k) {
        const float wgt = ((k & 4) ? w0 : 1.0f - w0) *
                          ((k & 2) ? w1 : 1.0f - w1) *
                          ((k & 1) ? w2 : 1.0f - w2);
        const float2 f = unpack_bf16x2(fv[k]);
        c0 += wgt * f.x;
        c1 += wgt * f.y;
    }
}

// ---- pass 0: fat kernel = Morton histogram || table fp32->bf16x2 convert ---
__global__ __launch_bounds__(256)
void hist_conv_kernel(const float* __restrict__ x, int* __restrict__ rank,
                      unsigned* __restrict__ hist,
                      const float* __restrict__ tables,
                      unsigned* __restrict__ tb)
{
    if (blockIdx.x < NBLOCKS) {
        const int p = blockIdx.x * 256 + threadIdx.x;
        if (p >= N_POINTS) return;
        const float x0 = x[3 * p], x1 = x[3 * p + 1], x2 = x[3 * p + 2];
        const bool inbox = (x0 >= -1.f) & (x0 <= 1.f) &
                           (x1 >= -1.f) & (x1 <= 1.f) &
                           (x2 >= -1.f) & (x2 <= 1.f);
        if (inbox) {
            const int cell = morton_cell(x0, x1, x2);
            atomicAdd(&hist[cell], 1u);
            rank[p] = cell;
        } else {
            rank[p] = -1;
        }
    } else {
        const unsigned nthr = CONV_BLOCKS * 256;
        for (unsigned e4 = (blockIdx.x - NBLOCKS) * 256 + threadIdx.x;
             e4 < (N_ENTRIES / 4); e4 += nthr) {
            const float4 a = ((const float4*)tables)[2 * e4];
            const float4 b = ((const float4*)tables)[2 * e4 + 1];
            uint4 o;
            o.x = pack_bf16x2(a.x, a.y);
            o.y = pack_bf16x2(a.z, a.w);
            o.z = pack_bf16x2(b.x, b.y);
            o.w = pack_bf16x2(b.z, b.w);
            ((uint4*)tb)[e4] = o;
        }
    }
}

// ---- pass 0.5: single-block exclusive scan (vectorized uint4 I/O) ----------
__global__ __launch_bounds__(1024)
void scan_kernel(unsigned* __restrict__ hist, unsigned* __restrict__ counter)
{
    __shared__ unsigned partial[1024];
    const int tid = threadIdx.x;
    uint4* __restrict__ hp = (uint4*)hist + tid * 8;   // 32 cells = 8 uint4
    uint4 vv[8];
    unsigned s = 0;
    #pragma unroll
    for (int i = 0; i < 8; ++i) {
        vv[i] = hp[i];
        s += vv[i].x + vv[i].y + vv[i].z + vv[i].w;
    }
    partial[tid] = s;
    __syncthreads();
    for (int off = 1; off < 1024; off <<= 1) {
        unsigned t = (tid >= off) ? partial[tid - off] : 0u;
        __syncthreads();
        partial[tid] += t;
        __syncthreads();
    }
    if (tid == 1023) counter[0] = partial[1023];
    unsigned run = partial[tid] - s;           // exclusive prefix
    #pragma unroll
    for (int i = 0; i < 8; ++i) {
        uint4 o;
        o.x = run; run += vv[i].x;
        o.y = run; run += vv[i].y;
        o.z = run; run += vv[i].z;
        o.w = run; run += vv[i].w;
        hp[i] = o;
    }
}

// ---- pass 0.75: scatter points into Morton-sorted order --------------------
// Stores the ORIGINAL point index in xw.w (bit-cast) for the tail.
__global__ __launch_bounds__(256)
void scatter_kernel(const float* __restrict__ x, int* __restrict__ rank,
                    float4* __restrict__ xw, unsigned* __restrict__ hist)
{
    const int p = blockIdx.x * 256 + threadIdx.x;
    if (p >= N_POINTS) return;
    const int cell = rank[p];
    if (cell < 0) return;                      // rank stays -1
    const unsigned rk = atomicAdd(&hist[cell], 1u);
    rank[p] = (int)rk;
    xw[rk] = make_float4(x[3 * p], x[3 * p + 1], x[3 * p + 2],
                         __int_as_float(p));
}

// ---- pass 1: actual-line-balanced schedule (3-constraint model) -------------
// Model fitting R2..R8: (1) TA issue ~1.5 nominal lane-req/cy/CU (R8's G7
// with 6 light levels: 15.3M/32/1.5 = 319k cy = 134 us, the R8 limiter);
// (2) L2 random-line service ~19.3/cy/XCD (R2's G7 = 5.1M/19.3 = 264k cy
// = 110 us, the R2 limiter); (3) misses ~0.45 cy/line + thrash multiplier
// (R5: +1.8M-line FETCH -> 122 us). This schedule balances ACTUAL lines
// (L0-6 per point: .125,.19,.33,.66,1.33,2.9,6.6; L7-15: 8) by slicing only
// L8 and L9 across the slack groups (replication +12 MB only). All groups
// land ~170-180k cy ~= 74 us + slice misses. Task-major loop keeps one
// table hot per XCD.
__global__ __launch_bounds__(256)
void fused_levels_kernel(const float4* __restrict__ xw,
                         const unsigned* __restrict__ counter,
                         const unsigned* __restrict__ tb,
                         unsigned* __restrict__ ws2, ResArr res, TaskTab tt)
{
    const unsigned k    = blockIdx.x & 7;
    const unsigned bix  = blockIdx.x >> 3;
    const unsigned nbx  = gridDim.x >> 3;
    const unsigned cnt  = *counter;

    #pragma unroll 1
    for (int tix = 0; tix < tt.n[k]; ++tix) {
        const int g = tt.t[k][tix].g;
        const unsigned lo =
            (unsigned)(((unsigned long long)tt.t[k][tix].lo * cnt) >> 8);
        const unsigned hi =
            (unsigned)(((unsigned long long)tt.t[k][tix].hi * cnt) >> 8);
        const unsigned len = hi - lo;
        if (!len) continue;
        const unsigned per = (len + nbx - 1) / nbx;
        const unsigned s0  = lo + bix * per;
        const unsigned s1  = min(hi, s0 + per);

        const float r = res.r[g];
        const unsigned* __restrict__ tbl = tb + ((size_t)g << LOG2_T);
        unsigned* __restrict__ wrow = ws2 + (size_t)g * N_POINTS;
        for (unsigned i = s0 + threadIdx.x; i < s1; i += 256) {
            const float4 v = xw[i];
            float c0, c1;
            gather_level_bf16(v.x, v.y, v.z, r, tbl, c0, c1);
            wrow[i] = pack_bf16x2(c0, c1);
        }
    }
}

// ---- pass 2: tail -----------------------------------------------------------
// Part A: zero-fill rows of out-of-box points (orig order, predicated).
// Part B: iterate SORTED index -> ws2 reads; 8 threads/point write the
// 128 B output row contiguously (random writes are fire-and-forget).
__global__ __launch_bounds__(256)
void tail_kernel(const int* __restrict__ rank, const float4* __restrict__ xw,
                 const unsigned* __restrict__ counter,
                 const unsigned* __restrict__ ws2, float* __restrict__ out)
{
    const int t = threadIdx.x;
    if (blockIdx.x < NBLOCKS) {
        const int P0 = blockIdx.x * 256;
        float4* __restrict__ out4 = (float4*)out + (size_t)P0 * 8;
        const float4 z = make_float4(0.f, 0.f, 0.f, 0.f);
        #pragma unroll
        for (int i = 0; i < 8; ++i) {
            const int j  = i * 256 + t;
            const int pp = P0 + (j >> 3);
            if (pp < N_POINTS && rank[pp] < 0) out4[j] = z;
        }
    } else {
        const unsigned cnt = *counter;
        const unsigned tot = cnt * 8u;
        const unsigned bix = blockIdx.x - NBLOCKS;
        for (unsigned tg = bix * 256 + t; tg < tot; tg += TAILB_BLOCKS * 256) {
            const unsigned i = tg >> 3, q = tg & 7;
            const unsigned a = ws2[(size_t)(2 * q) * N_POINTS + i];
            const unsigned b = ws2[(size_t)(2 * q + 1) * N_POINTS + i];
            const int p = __float_as_int(xw[i].w);
            const float2 fa = unpack_bf16x2(a);
            const float2 fb = unpack_bf16x2(b);
            ((float4*)out)[(size_t)p * 8 + q] =
                make_float4(fa.x, fa.y, fb.x, fb.y);
        }
    }
}

// ---- fallback (ws too small): R1-style monolithic kernel (fp32 tables) -----
__device__ __forceinline__ void gather_level_f32(
    float x0, float x1, float x2, float r,
    const float2* __restrict__ tbl, float& c0, float& c1)
{
    const float xn0 = (x0 + 1.0f) * 0.5f * r;
    const float xn1 = (x1 + 1.0f) * 0.5f * r;
    const float xn2 = (x2 + 1.0f) * 0.5f * r;
    const float f0 = floorf(xn0), f1 = floorf(xn1), f2 = floorf(xn2);
    const unsigned v0 = (unsigned)(int)f0;
    const unsigned v1 = (unsigned)(int)f1;
    const unsigned v2 = (unsigned)(int)f2;
    const float w0 = xn0 - f0, w1 = xn1 - f1, w2 = xn2 - f2;
    c0 = 0.f; c1 = 0.f;
    #pragma unroll
    for (int k = 0; k < 8; ++k) {
        const unsigned vx = v0 + ((k >> 2) & 1);
        const unsigned vy = v1 + ((k >> 1) & 1);
        const unsigned vz = v2 + (k & 1);
        unsigned h = (vx * 1u) ^ (vy * 2654435761u) ^ (vz * 805459861u);
        h &= TABLE_MASK;
        const float wgt = ((k & 4) ? w0 : 1.0f - w0) *
                          ((k & 2) ? w1 : 1.0f - w1) *
                          ((k & 1) ? w2 : 1.0f - w2);
        const float2 f = tbl[h];
        c0 += wgt * f.x;
        c1 += wgt * f.y;
    }
}

__global__ __launch_bounds__(256)
void mono_kernel(const float* __restrict__ x, const float* __restrict__ tables,
                 float* __restrict__ out, ResArr res)
{
    int idx = blockIdx.x * blockDim.x + threadIdx.x;
    if (idx >= N_POINTS * N_GRIDS) return;
    int b = idx >> 4, g = idx & 15;
    float x0 = x[b * 3], x1 = x[b * 3 + 1], x2 = x[b * 3 + 2];
    bool inbox = (x0 >= -1.f) & (x0 <= 1.f) & (x1 >= -1.f) & (x1 <= 1.f) &
                 (x2 >= -1.f) & (x2 <= 1.f);
    float c0 = 0.f, c1 = 0.f;
    if (inbox) {
        const float2* tbl = (const float2*)tables + ((size_t)g << LOG2_T);
        gather_level_f32(x0, x1, x2, res.r[g], tbl, c0, c1);
    }
    ((float2*)out)[(size_t)b * N_GRIDS + g] = make_float2(c0, c1);
}

extern "C" void kernel_launch(void* const* d_in, const int* in_sizes, int n_in,
                              void* d_out, int out_size, void* d_ws, size_t ws_size,
                              hipStream_t stream)
{
    const float* x      = (const float*)d_in[0];
    const float* tables = (const float*)d_in[1];
    float* out          = (float*)d_out;

    ResArr res;
    double pls = exp((log(2048.0) - log(16.0)) / 15.0);
    for (int i = 0; i < N_GRIDS; ++i)
        res.r[i] = (float)floor(16.0 * pow(pls, (double)i));

    // ---- actual-line-balanced task table (order: light, heavy, slices) ----
    TaskTab tt;
    for (int k = 0; k < 8; ++k) tt.n[k] = 0;
    auto add = [&](int grp, int g, int lo, int hi) {
        tt.t[grp][tt.n[grp]].g  = g;
        tt.t[grp][tt.n[grp]].lo = lo;
        tt.t[grp][tt.n[grp]].hi = hi;
        tt.n[grp]++;
    };
    add(0, 0, 0, 256);  add(0, 15, 0, 256);  add(0, 8, 87, 170);
    add(1, 1, 0, 256);  add(1, 14, 0, 256);  add(1, 8, 170, 251);
    add(2, 2, 0, 256);  add(2, 13, 0, 256);  add(2, 8, 251, 256);
                                             add(2, 9, 0, 72);
    add(3, 3, 0, 256);  add(3, 12, 0, 256);  add(3, 9, 72, 124);
    add(4, 4, 0, 256);  add(4, 11, 0, 256);
    add(5, 5, 0, 256);  add(5, 10, 0, 256);
    add(6, 6, 0, 256);  add(6, 9, 124, 256);
    add(7, 7, 0, 256);  add(7, 8, 0, 87);

    // ws layout:
    // [counter 256B][hist 128KB][rank 4MB][xw 16MB][ws2 64MB][tb 33.6MB]
    const size_t off_hist = 256;
    const size_t off_rank = off_hist + (size_t)N_CELLS * 4;
    const size_t off_xw   = off_rank + (size_t)N_POINTS * 4;
    const size_t off_ws2  = off_xw + (size_t)N_POINTS * 16;
    const size_t off_tb   = off_ws2 + (size_t)N_GRIDS * N_POINTS * 4;
    const size_t ws_needed = off_tb + (size_t)N_ENTRIES * 4;

    if (ws_size < ws_needed) {
        int total = N_POINTS * N_GRIDS;
        mono_kernel<<<(total + 255) / 256, 256, 0, stream>>>(x, tables, out, res);
        return;
    }

    char* w = (char*)d_ws;
    unsigned* counter = (unsigned*)w;
    unsigned* hist    = (unsigned*)(w + off_hist);
    int*      rank    = (int*)(w + off_rank);
    float4*   xw      = (float4*)(w + off_xw);
    unsigned* ws2     = (unsigned*)(w + off_ws2);
    unsigned* tb      = (unsigned*)(w + off_tb);

    (void)hipMemsetAsync(w, 0, off_rank, stream);   // counter + hist
    hist_conv_kernel<<<NBLOCKS + CONV_BLOCKS, 256, 0, stream>>>(
        x, rank, hist, tables, tb);
    scan_kernel<<<1, 1024, 0, stream>>>(hist, counter);
    scatter_kernel<<<NBLOCKS, 256, 0, stream>>>(x, rank, xw, hist);
    fused_levels_kernel<<<FUSED_BLOCKS, 256, 0, stream>>>(xw, counter, tb,
                                                          ws2, res, tt);
    tail_kernel<<<NBLOCKS + TAILB_BLOCKS, 256, 0, stream>>>(rank, xw, counter,
                                                            ws2, out);
}

// Round 10
// 177.664 us; speedup vs baseline: 1.2429x; 1.1712x over previous
//
#include <hip/hip_runtime.h>
#include <hip/hip_bf16.h>
#include <math.h>

#define N_POINTS 1000000
#define N_GRIDS  16
#define LOG2_T   19
#define TABLE_MASK ((1u << LOG2_T) - 1u)
#define NBLOCKS  ((N_POINTS + 255) / 256)
#define CONV_BLOCKS 4096
#define FUSED_BLOCKS 2048          // multiple of 8; 8 groups -> 8 XCDs
#define TAILB_BLOCKS 4096
#define N_ENTRIES (N_GRIDS << LOG2_T)   // 8.4M bf16x2 entries
#define NCELL_AX 32                // Morton bucket grid 32^3
#define N_CELLS  (NCELL_AX * NCELL_AX * NCELL_AX)   // 32768

struct ResArr { float r[N_GRIDS]; };

__device__ __forceinline__ unsigned pack_bf16x2(float a, float b)
{
    __hip_bfloat16 ha = __float2bfloat16(a);
    __hip_bfloat16 hb = __float2bfloat16(b);
    unsigned short ua = *(unsigned short*)&ha;
    unsigned short ub = *(unsigned short*)&hb;
    return (unsigned)ua | ((unsigned)ub << 16);
}

__device__ __forceinline__ float2 unpack_bf16x2(unsigned v)
{
    unsigned lo = (v & 0xffffu) << 16;
    unsigned hi = v & 0xffff0000u;
    return make_float2(__uint_as_float(lo), __uint_as_float(hi));
}

// 5-bit -> every-3rd-bit expansion for Morton codes
__device__ __forceinline__ unsigned expand_bits(unsigned v)
{
    v &= 0x3ffu;
    v = (v | (v << 16)) & 0x30000FFu;
    v = (v | (v << 8))  & 0x300F00Fu;
    v = (v | (v << 4))  & 0x30C30C3u;
    v = (v | (v << 2))  & 0x9249249u;
    return v;
}

__device__ __forceinline__ int morton_cell(float x0, float x1, float x2)
{
    int cx = (int)floorf((x0 + 1.f) * 16.f);
    int cy = (int)floorf((x1 + 1.f) * 16.f);
    int cz = (int)floorf((x2 + 1.f) * 16.f);
    cx = min(NCELL_AX - 1, max(0, cx));
    cy = min(NCELL_AX - 1, max(0, cy));
    cz = min(NCELL_AX - 1, max(0, cz));
    return (int)((expand_bits((unsigned)cx) << 2) |
                 (expand_bits((unsigned)cy) << 1) |
                  expand_bits((unsigned)cz));
}

// gather with x-pair INSTRUCTION merging. PRIMES[0]==1 -> sb = sa ^ d with
// d = v0^(v0+1). When v0 even (50%), d==1 and both x-corners sit in the same
// aligned uint2 -> ONE 8B load serves both. Otherwise a predicated 4B load
// fetches the second corner (only lanes with d!=1 issue requests).
// 8 -> ~6 lane-requests per point-level (-25% L2 request slots).
// Accumulation loop is k-order identical to R2 -> bit-exact results.
__device__ __forceinline__ void gather_level_bf16(
    float x0, float x1, float x2, float r,
    const unsigned* __restrict__ tbl, float& c0, float& c1)
{
    // match reference: (x + 1.0) * 0.5 * r, left-to-right fp32
    const float xn0 = (x0 + 1.0f) * 0.5f * r;
    const float xn1 = (x1 + 1.0f) * 0.5f * r;
    const float xn2 = (x2 + 1.0f) * 0.5f * r;
    const float f0 = floorf(xn0), f1 = floorf(xn1), f2 = floorf(xn2);
    const unsigned v0 = (unsigned)(int)f0;
    const unsigned v1 = (unsigned)(int)f1;
    const unsigned v2 = (unsigned)(int)f2;
    const float w0 = xn0 - f0, w1 = xn1 - f1, w2 = xn2 - f2;
    const unsigned d = v0 ^ (v0 + 1u);     // 2^t - 1, ==1 for even v0

    unsigned sa4[4];
    uint2    pa[4];
    #pragma unroll
    for (int yz = 0; yz < 4; ++yz) {
        const unsigned vy = v1 + ((yz >> 1) & 1);
        const unsigned vz = v2 + (yz & 1);
        const unsigned m  = (vy * 2654435761u) ^ (vz * 805459861u);
        const unsigned sa = (v0 ^ m) & TABLE_MASK;
        sa4[yz] = sa;
        pa[yz]  = ((const uint2*)tbl)[sa >> 1];   // covers slots {sa&~1, sa|1}
    }
    const bool paired = (d == 1u);
    unsigned ub[4];
    #pragma unroll
    for (int yz = 0; yz < 4; ++yz) {
        unsigned u = 0;
        if (!paired) u = tbl[(sa4[yz] ^ d) & TABLE_MASK];  // predicated load
        ub[yz] = u;
    }

    unsigned fv[8];
    #pragma unroll
    for (int yz = 0; yz < 4; ++yz) {
        const unsigned odd = sa4[yz] & 1u;
        const unsigned uA = odd ? pa[yz].y : pa[yz].x;     // slot sa
        const unsigned uB = paired ? (odd ? pa[yz].x : pa[yz].y)  // slot sa^1
                                   : ub[yz];
        fv[yz]     = uA;   // k = yz   (x-corner 0)
        fv[4 + yz] = uB;   // k = 4+yz (x-corner 1)
    }

    c0 = 0.f; c1 = 0.f;
    #pragma unroll
    for (int k = 0; k < 8; ++k) {
        const float wgt = ((k & 4) ? w0 : 1.0f - w0) *
                          ((k & 2) ? w1 : 1.0f - w1) *
                          ((k & 1) ? w2 : 1.0f - w2);
        const float2 f = unpack_bf16x2(fv[k]);
        c0 += wgt * f.x;
        c1 += wgt * f.y;
    }
}

// ---- pass 0: Morton histogram; caches each point's cell id in rank[] -------
__global__ __launch_bounds__(256)
void hist_kernel(const float* __restrict__ x, int* __restrict__ rank,
                 unsigned* __restrict__ hist)
{
    const int p = blockIdx.x * 256 + threadIdx.x;
    if (p >= N_POINTS) return;
    const float x0 = x[3 * p], x1 = x[3 * p + 1], x2 = x[3 * p + 2];
    const bool inbox = (x0 >= -1.f) & (x0 <= 1.f) &
                       (x1 >= -1.f) & (x1 <= 1.f) &
                       (x2 >= -1.f) & (x2 <= 1.f);
    if (inbox) {
        const int cell = morton_cell(x0, x1, x2);
        atomicAdd(&hist[cell], 1u);
        rank[p] = cell;
    } else {
        rank[p] = -1;
    }
}

// ---- pass 0.5: single-block exclusive scan (vectorized uint4 I/O) ----------
__global__ __launch_bounds__(1024)
void scan_kernel(unsigned* __restrict__ hist, unsigned* __restrict__ counter)
{
    __shared__ unsigned partial[1024];
    const int tid = threadIdx.x;
    uint4* __restrict__ hp = (uint4*)hist + tid * 8;   // 32 cells = 8 uint4
    uint4 vv[8];
    unsigned s = 0;
    #pragma unroll
    for (int i = 0; i < 8; ++i) {
        vv[i] = hp[i];
        s += vv[i].x + vv[i].y + vv[i].z + vv[i].w;
    }
    partial[tid] = s;
    __syncthreads();
    for (int off = 1; off < 1024; off <<= 1) {
        unsigned t = (tid >= off) ? partial[tid - off] : 0u;
        __syncthreads();
        partial[tid] += t;
        __syncthreads();
    }
    if (tid == 1023) counter[0] = partial[1023];
    unsigned run = partial[tid] - s;           // exclusive prefix
    #pragma unroll
    for (int i = 0; i < 8; ++i) {
        uint4 o;
        o.x = run; run += vv[i].x;
        o.y = run; run += vv[i].y;
        o.z = run; run += vv[i].z;
        o.w = run; run += vv[i].w;
        hp[i] = o;
    }
}

// ---- pass 0.75: fat kernel = table convert || Morton scatter ---------------
// Scatter (atomic/latency-bound) and fp32->bf16x2 convert (bandwidth-bound)
// overlap. Scatter stores the ORIGINAL point index in xw.w (bit-cast).
__global__ __launch_bounds__(256)
void scatter_conv_kernel(const float* __restrict__ tables,
                         unsigned* __restrict__ tb,
                         const float* __restrict__ x, int* __restrict__ rank,
                         float4* __restrict__ xw, unsigned* __restrict__ hist)
{
    if (blockIdx.x < CONV_BLOCKS) {
        const unsigned nthr = CONV_BLOCKS * 256;
        for (unsigned e4 = blockIdx.x * 256 + threadIdx.x; e4 < (N_ENTRIES / 4);
             e4 += nthr) {
            const float4 a = ((const float4*)tables)[2 * e4];
            const float4 b = ((const float4*)tables)[2 * e4 + 1];
            uint4 o;
            o.x = pack_bf16x2(a.x, a.y);
            o.y = pack_bf16x2(a.z, a.w);
            o.z = pack_bf16x2(b.x, b.y);
            o.w = pack_bf16x2(b.z, b.w);
            ((uint4*)tb)[e4] = o;
        }
    } else {
        const int p = (blockIdx.x - CONV_BLOCKS) * 256 + threadIdx.x;
        if (p >= N_POINTS) return;
        const int cell = rank[p];
        if (cell < 0) return;                  // rank stays -1
        const unsigned rk = atomicAdd(&hist[cell], 1u);
        rank[p] = (int)rk;
        xw[rk] = make_float4(x[3 * p], x[3 * p + 1], x[3 * p + 2],
                             __int_as_float(p));
    }
}

// ---- pass 1: R2-exact schedule (measured best across 5 schedule variants) --
// 2 levels per XCD group, paired (k,15-k), block-contiguous chunks, task-
// major. R4/R5/R8/R9 balance attempts all lost what they gained: splitting a
// hashed table across XCDs converts L2 hits to misses (latency up cancels
// requests down). Only the gather itself changed this round.
__global__ __launch_bounds__(256)
void fused_levels_kernel(const float4* __restrict__ xw,
                         const unsigned* __restrict__ counter,
                         const unsigned* __restrict__ tb,
                         unsigned* __restrict__ ws2, ResArr res)
{
    const unsigned k    = blockIdx.x & 7;
    const unsigned bix  = blockIdx.x >> 3;
    const unsigned nbx  = gridDim.x >> 3;
    const unsigned cnt  = *counter;
    const unsigned per  = (cnt + nbx - 1) / nbx;
    const unsigned lo   = bix * per;
    const unsigned hi   = min(cnt, lo + per);

    #pragma unroll 1
    for (int t = 0; t < 2; ++t) {
        const int g = t ? (15 - (int)k) : (int)k;
        const float r = res.r[g];
        const unsigned* __restrict__ tbl = tb + ((size_t)g << LOG2_T);
        unsigned* __restrict__ wrow = ws2 + (size_t)g * N_POINTS;
        for (unsigned i = lo + threadIdx.x; i < hi; i += 256) {
            const float4 v = xw[i];
            float c0, c1;
            gather_level_bf16(v.x, v.y, v.z, r, tbl, c0, c1);
            wrow[i] = pack_bf16x2(c0, c1);
        }
    }
}

// ---- pass 2: tail -----------------------------------------------------------
// Part A: zero-fill rows of out-of-box points (orig order, predicated).
// Part B: iterate SORTED index -> coalesced ws2 reads; 8 threads/point write
// the 128 B output row contiguously (random writes are fire-and-forget).
__global__ __launch_bounds__(256)
void tail_kernel(const int* __restrict__ rank, const float4* __restrict__ xw,
                 const unsigned* __restrict__ counter,
                 const unsigned* __restrict__ ws2, float* __restrict__ out)
{
    const int t = threadIdx.x;
    if (blockIdx.x < NBLOCKS) {
        const int P0 = blockIdx.x * 256;
        float4* __restrict__ out4 = (float4*)out + (size_t)P0 * 8;
        const float4 z = make_float4(0.f, 0.f, 0.f, 0.f);
        #pragma unroll
        for (int i = 0; i < 8; ++i) {
            const int j  = i * 256 + t;
            const int pp = P0 + (j >> 3);
            if (pp < N_POINTS && rank[pp] < 0) out4[j] = z;
        }
    } else {
        const unsigned cnt = *counter;
        const unsigned tot = cnt * 8u;
        const unsigned bix = blockIdx.x - NBLOCKS;
        for (unsigned tg = bix * 256 + t; tg < tot; tg += TAILB_BLOCKS * 256) {
            const unsigned i = tg >> 3, q = tg & 7;
            const unsigned a = ws2[(size_t)(2 * q) * N_POINTS + i];
            const unsigned b = ws2[(size_t)(2 * q + 1) * N_POINTS + i];
            const int p = __float_as_int(xw[i].w);
            const float2 fa = unpack_bf16x2(a);
            const float2 fb = unpack_bf16x2(b);
            ((float4*)out)[(size_t)p * 8 + q] =
                make_float4(fa.x, fa.y, fb.x, fb.y);
        }
    }
}

// ---- fallback (ws too small): R1-style monolithic kernel (fp32 tables) -----
__device__ __forceinline__ void gather_level_f32(
    float x0, float x1, float x2, float r,
    const float2* __restrict__ tbl, float& c0, float& c1)
{
    const float xn0 = (x0 + 1.0f) * 0.5f * r;
    const float xn1 = (x1 + 1.0f) * 0.5f * r;
    const float xn2 = (x2 + 1.0f) * 0.5f * r;
    const float f0 = floorf(xn0), f1 = floorf(xn1), f2 = floorf(xn2);
    const unsigned v0 = (unsigned)(int)f0;
    const unsigned v1 = (unsigned)(int)f1;
    const unsigned v2 = (unsigned)(int)f2;
    const float w0 = xn0 - f0, w1 = xn1 - f1, w2 = xn2 - f2;
    c0 = 0.f; c1 = 0.f;
    #pragma unroll
    for (int k = 0; k < 8; ++k) {
        const unsigned vx = v0 + ((k >> 2) & 1);
        const unsigned vy = v1 + ((k >> 1) & 1);
        const unsigned vz = v2 + (k & 1);
        unsigned h = (vx * 1u) ^ (vy * 2654435761u) ^ (vz * 805459861u);
        h &= TABLE_MASK;
        const float wgt = ((k & 4) ? w0 : 1.0f - w0) *
                          ((k & 2) ? w1 : 1.0f - w1) *
                          ((k & 1) ? w2 : 1.0f - w2);
        const float2 f = tbl[h];
        c0 += wgt * f.x;
        c1 += wgt * f.y;
    }
}

__global__ __launch_bounds__(256)
void mono_kernel(const float* __restrict__ x, const float* __restrict__ tables,
                 float* __restrict__ out, ResArr res)
{
    int idx = blockIdx.x * blockDim.x + threadIdx.x;
    if (idx >= N_POINTS * N_GRIDS) return;
    int b = idx >> 4, g = idx & 15;
    float x0 = x[b * 3], x1 = x[b * 3 + 1], x2 = x[b * 3 + 2];
    bool inbox = (x0 >= -1.f) & (x0 <= 1.f) & (x1 >= -1.f) & (x1 <= 1.f) &
                 (x2 >= -1.f) & (x2 <= 1.f);
    float c0 = 0.f, c1 = 0.f;
    if (inbox) {
        const float2* tbl = (const float2*)tables + ((size_t)g << LOG2_T);
        gather_level_f32(x0, x1, x2, res.r[g], tbl, c0, c1);
    }
    ((float2*)out)[(size_t)b * N_GRIDS + g] = make_float2(c0, c1);
}

extern "C" void kernel_launch(void* const* d_in, const int* in_sizes, int n_in,
                              void* d_out, int out_size, void* d_ws, size_t ws_size,
                              hipStream_t stream)
{
    const float* x      = (const float*)d_in[0];
    const float* tables = (const float*)d_in[1];
    float* out          = (float*)d_out;

    ResArr res;
    double pls = exp((log(2048.0) - log(16.0)) / 15.0);
    for (int i = 0; i < N_GRIDS; ++i)
        res.r[i] = (float)floor(16.0 * pow(pls, (double)i));

    // ws layout:
    // [counter 256B][hist 128KB][rank 4MB][xw 16MB][ws2 64MB][tb 33.6MB]
    const size_t off_hist = 256;
    const size_t off_rank = off_hist + (size_t)N_CELLS * 4;
    const size_t off_xw   = off_rank + (size_t)N_POINTS * 4;
    const size_t off_ws2  = off_xw + (size_t)N_POINTS * 16;
    const size_t off_tb   = off_ws2 + (size_t)N_GRIDS * N_POINTS * 4;
    const size_t ws_needed = off_tb + (size_t)N_ENTRIES * 4;

    if (ws_size < ws_needed) {
        int total = N_POINTS * N_GRIDS;
        mono_kernel<<<(total + 255) / 256, 256, 0, stream>>>(x, tables, out, res);
        return;
    }

    char* w = (char*)d_ws;
    unsigned* counter = (unsigned*)w;
    unsigned* hist    = (unsigned*)(w + off_hist);
    int*      rank    = (int*)(w + off_rank);
    float4*   xw      = (float4*)(w + off_xw);
    unsigned* ws2     = (unsigned*)(w + off_ws2);
    unsigned* tb      = (unsigned*)(w + off_tb);

    (void)hipMemsetAsync(w, 0, off_rank, stream);   // counter + hist
    hist_kernel<<<NBLOCKS, 256, 0, stream>>>(x, rank, hist);
    scan_kernel<<<1, 1024, 0, stream>>>(hist, counter);
    scatter_conv_kernel<<<CONV_BLOCKS + NBLOCKS, 256, 0, stream>>>(
        tables, tb, x, rank, xw, hist);
    fused_levels_kernel<<<FUSED_BLOCKS, 256, 0, stream>>>(xw, counter, tb,
                                                          ws2, res);
    tail_kernel<<<NBLOCKS + TAILB_BLOCKS, 256, 0, stream>>>(rank, xw, counter,
                                                            ws2, out);
}

// Round 11
// 172.179 us; speedup vs baseline: 1.2825x; 1.0319x over previous
//
#include <hip/hip_runtime.h>
#include <hip/hip_bf16.h>
#include <math.h>

#define N_POINTS 1000000
#define N_GRIDS  16
#define LOG2_T   19
#define TABLE_MASK ((1u << LOG2_T) - 1u)
#define NBLOCKS  ((N_POINTS + 255) / 256)
#define CONV_BLOCKS 4096
#define FUSED_BLOCKS 2048          // multiple of 8; 8 groups -> 8 XCDs
#define TAILB_BLOCKS 4096
#define N_ENTRIES (N_GRIDS << LOG2_T)   // 8.4M bf16x2 entries
#define NCELL_AX 32                // Morton bucket grid 32^3
#define N_CELLS  (NCELL_AX * NCELL_AX * NCELL_AX)   // 32768

struct ResArr { float r[N_GRIDS]; };

__device__ __forceinline__ unsigned pack_bf16x2(float a, float b)
{
    __hip_bfloat16 ha = __float2bfloat16(a);
    __hip_bfloat16 hb = __float2bfloat16(b);
    unsigned short ua = *(unsigned short*)&ha;
    unsigned short ub = *(unsigned short*)&hb;
    return (unsigned)ua | ((unsigned)ub << 16);
}

__device__ __forceinline__ float2 unpack_bf16x2(unsigned v)
{
    unsigned lo = (v & 0xffffu) << 16;
    unsigned hi = v & 0xffff0000u;
    return make_float2(__uint_as_float(lo), __uint_as_float(hi));
}

// 5-bit -> every-3rd-bit expansion for Morton codes
__device__ __forceinline__ unsigned expand_bits(unsigned v)
{
    v &= 0x3ffu;
    v = (v | (v << 16)) & 0x30000FFu;
    v = (v | (v << 8))  & 0x300F00Fu;
    v = (v | (v << 4))  & 0x30C30C3u;
    v = (v | (v << 2))  & 0x9249249u;
    return v;
}

__device__ __forceinline__ int morton_cell(float x0, float x1, float x2)
{
    int cx = (int)floorf((x0 + 1.f) * 16.f);
    int cy = (int)floorf((x1 + 1.f) * 16.f);
    int cz = (int)floorf((x2 + 1.f) * 16.f);
    cx = min(NCELL_AX - 1, max(0, cx));
    cy = min(NCELL_AX - 1, max(0, cy));
    cz = min(NCELL_AX - 1, max(0, cz));
    return (int)((expand_bits((unsigned)cx) << 2) |
                 (expand_bits((unsigned)cy) << 1) |
                  expand_bits((unsigned)cz));
}

__device__ __forceinline__ unsigned sel4(uint4 P, unsigned idx)
{
    const unsigned lo = (idx & 1u) ? P.y : P.x;
    const unsigned hi = (idx & 1u) ? P.w : P.z;
    return (idx & 2u) ? hi : lo;
}

// gather with uint4 corner-pair loads. PRIMES[0]==1 -> the two x-corner
// slots are {sa, sa^d}, d = v0^(v0+1). For d<=3 (v0 mod 4 in {0,1,2}: 75%
// of lanes) both slots lie in the SAME aligned 4-slot group -> one uint4
// load serves both corners. Only d>=7 lanes (25%) issue a predicated 4 B
// load for the second corner. Avg lane-requests: 8 (R2) -> 6 (R10) -> 5.
// R10 confirmed requests are the currency (110 -> 93 us from 8 -> 6).
// fv content and fma order identical to R2 -> bit-exact results.
__device__ __forceinline__ void gather_level_bf16(
    float x0, float x1, float x2, float r,
    const unsigned* __restrict__ tbl, float& c0, float& c1)
{
    // match reference: (x + 1.0) * 0.5 * r, left-to-right fp32
    const float xn0 = (x0 + 1.0f) * 0.5f * r;
    const float xn1 = (x1 + 1.0f) * 0.5f * r;
    const float xn2 = (x2 + 1.0f) * 0.5f * r;
    const float f0 = floorf(xn0), f1 = floorf(xn1), f2 = floorf(xn2);
    const unsigned v0 = (unsigned)(int)f0;
    const unsigned v1 = (unsigned)(int)f1;
    const unsigned v2 = (unsigned)(int)f2;
    const float w0 = xn0 - f0, w1 = xn1 - f1, w2 = xn2 - f2;
    const unsigned d = v0 ^ (v0 + 1u);     // 2^t - 1

    unsigned sa4[4];
    uint4    pa[4];
    #pragma unroll
    for (int yz = 0; yz < 4; ++yz) {
        const unsigned vy = v1 + ((yz >> 1) & 1);
        const unsigned vz = v2 + (yz & 1);
        const unsigned m  = (vy * 2654435761u) ^ (vz * 805459861u);
        const unsigned sa = (v0 ^ m) & TABLE_MASK;
        sa4[yz] = sa;
        pa[yz]  = ((const uint4*)tbl)[sa >> 2];   // aligned 4-slot group
    }
    const bool far = (d > 3u);             // 25% of lanes
    unsigned ub[4];
    #pragma unroll
    for (int yz = 0; yz < 4; ++yz) {
        unsigned u = 0;
        if (far) u = tbl[(sa4[yz] ^ d) & TABLE_MASK];  // predicated load
        ub[yz] = u;
    }

    unsigned fv[8];
    #pragma unroll
    for (int yz = 0; yz < 4; ++yz) {
        const unsigned ia = sa4[yz] & 3u;
        const unsigned ib = (sa4[yz] ^ d) & 3u;        // valid when !far
        const unsigned uA = sel4(pa[yz], ia);          // slot sa
        const unsigned uB = far ? ub[yz] : sel4(pa[yz], ib);  // slot sa^d
        fv[yz]     = uA;   // k = yz   (x-corner 0)
        fv[4 + yz] = uB;   // k = 4+yz (x-corner 1)
    }

    c0 = 0.f; c1 = 0.f;
    #pragma unroll
    for (int k = 0; k < 8; ++k) {
        const float wgt = ((k & 4) ? w0 : 1.0f - w0) *
                          ((k & 2) ? w1 : 1.0f - w1) *
                          ((k & 1) ? w2 : 1.0f - w2);
        const float2 f = unpack_bf16x2(fv[k]);
        c0 += wgt * f.x;
        c1 += wgt * f.y;
    }
}

// ---- pass 0: Morton histogram + zero-fill of out-of-box output rows --------
// inbox is known here per-thread, so the 87 MB of zero rows overlap the
// atomic-latency-bound histogram instead of occupying the tail.
__global__ __launch_bounds__(256)
void hist_kernel(const float* __restrict__ x, int* __restrict__ rank,
                 unsigned* __restrict__ hist, float* __restrict__ out)
{
    const int p = blockIdx.x * 256 + threadIdx.x;
    if (p >= N_POINTS) return;
    const float x0 = x[3 * p], x1 = x[3 * p + 1], x2 = x[3 * p + 2];
    const bool inbox = (x0 >= -1.f) & (x0 <= 1.f) &
                       (x1 >= -1.f) & (x1 <= 1.f) &
                       (x2 >= -1.f) & (x2 <= 1.f);
    if (inbox) {
        const int cell = morton_cell(x0, x1, x2);
        atomicAdd(&hist[cell], 1u);
        rank[p] = cell;
    } else {
        rank[p] = -1;
        float4* __restrict__ row = (float4*)out + (size_t)p * 8;
        const float4 z = make_float4(0.f, 0.f, 0.f, 0.f);
        #pragma unroll
        for (int i = 0; i < 8; ++i) row[i] = z;
    }
}

// ---- pass 0.5: single-block exclusive scan (vectorized uint4 I/O) ----------
__global__ __launch_bounds__(1024)
void scan_kernel(unsigned* __restrict__ hist, unsigned* __restrict__ counter)
{
    __shared__ unsigned partial[1024];
    const int tid = threadIdx.x;
    uint4* __restrict__ hp = (uint4*)hist + tid * 8;   // 32 cells = 8 uint4
    uint4 vv[8];
    unsigned s = 0;
    #pragma unroll
    for (int i = 0; i < 8; ++i) {
        vv[i] = hp[i];
        s += vv[i].x + vv[i].y + vv[i].z + vv[i].w;
    }
    partial[tid] = s;
    __syncthreads();
    for (int off = 1; off < 1024; off <<= 1) {
        unsigned t = (tid >= off) ? partial[tid - off] : 0u;
        __syncthreads();
        partial[tid] += t;
        __syncthreads();
    }
    if (tid == 1023) counter[0] = partial[1023];
    unsigned run = partial[tid] - s;           // exclusive prefix
    #pragma unroll
    for (int i = 0; i < 8; ++i) {
        uint4 o;
        o.x = run; run += vv[i].x;
        o.y = run; run += vv[i].y;
        o.z = run; run += vv[i].z;
        o.w = run; run += vv[i].w;
        hp[i] = o;
    }
}

// ---- pass 0.75: fat kernel = table convert || Morton scatter ---------------
// Scatter stores the ORIGINAL point index in xw.w (bit-cast) for the tail.
// rank is no longer read downstream -> no rank update store.
__global__ __launch_bounds__(256)
void scatter_conv_kernel(const float* __restrict__ tables,
                         unsigned* __restrict__ tb,
                         const float* __restrict__ x,
                         const int* __restrict__ rank,
                         float4* __restrict__ xw, unsigned* __restrict__ hist)
{
    if (blockIdx.x < CONV_BLOCKS) {
        const unsigned nthr = CONV_BLOCKS * 256;
        for (unsigned e4 = blockIdx.x * 256 + threadIdx.x; e4 < (N_ENTRIES / 4);
             e4 += nthr) {
            const float4 a = ((const float4*)tables)[2 * e4];
            const float4 b = ((const float4*)tables)[2 * e4 + 1];
            uint4 o;
            o.x = pack_bf16x2(a.x, a.y);
            o.y = pack_bf16x2(a.z, a.w);
            o.z = pack_bf16x2(b.x, b.y);
            o.w = pack_bf16x2(b.z, b.w);
            ((uint4*)tb)[e4] = o;
        }
    } else {
        const int p = (blockIdx.x - CONV_BLOCKS) * 256 + threadIdx.x;
        if (p >= N_POINTS) return;
        const int cell = rank[p];
        if (cell < 0) return;
        const unsigned rk = atomicAdd(&hist[cell], 1u);
        xw[rk] = make_float4(x[3 * p], x[3 * p + 1], x[3 * p + 2],
                             __int_as_float(p));
    }
}

// ---- pass 1: R2-exact schedule (measured best across 5 schedule variants) --
// 2 levels per XCD group, paired (k,15-k), block-contiguous chunks.
__global__ __launch_bounds__(256)
void fused_levels_kernel(const float4* __restrict__ xw,
                         const unsigned* __restrict__ counter,
                         const unsigned* __restrict__ tb,
                         unsigned* __restrict__ ws2, ResArr res)
{
    const unsigned k    = blockIdx.x & 7;
    const unsigned bix  = blockIdx.x >> 3;
    const unsigned nbx  = gridDim.x >> 3;
    const unsigned cnt  = *counter;
    const unsigned per  = (cnt + nbx - 1) / nbx;
    const unsigned lo   = bix * per;
    const unsigned hi   = min(cnt, lo + per);

    #pragma unroll 1
    for (int t = 0; t < 2; ++t) {
        const int g = t ? (15 - (int)k) : (int)k;
        const float r = res.r[g];
        const unsigned* __restrict__ tbl = tb + ((size_t)g << LOG2_T);
        unsigned* __restrict__ wrow = ws2 + (size_t)g * N_POINTS;
        for (unsigned i = lo + threadIdx.x; i < hi; i += 256) {
            const float4 v = xw[i];
            float c0, c1;
            gather_level_bf16(v.x, v.y, v.z, r, tbl, c0, c1);
            wrow[i] = pack_bf16x2(c0, c1);
        }
    }
}

// ---- pass 2: sorted-domain tail (part B only; zero-fill moved to hist) -----
// Iterate SORTED index -> coalesced ws2 reads; 8 threads/point write the
// 128 B output row contiguously (random writes are fire-and-forget).
__global__ __launch_bounds__(256)
void tail_kernel(const float4* __restrict__ xw,
                 const unsigned* __restrict__ counter,
                 const unsigned* __restrict__ ws2, float* __restrict__ out)
{
    const int t = threadIdx.x;
    const unsigned cnt = *counter;
    const unsigned tot = cnt * 8u;
    for (unsigned tg = blockIdx.x * 256 + t; tg < tot;
         tg += TAILB_BLOCKS * 256) {
        const unsigned i = tg >> 3, q = tg & 7;
        const unsigned a = ws2[(size_t)(2 * q) * N_POINTS + i];
        const unsigned b = ws2[(size_t)(2 * q + 1) * N_POINTS + i];
        const int p = __float_as_int(xw[i].w);
        const float2 fa = unpack_bf16x2(a);
        const float2 fb = unpack_bf16x2(b);
        ((float4*)out)[(size_t)p * 8 + q] =
            make_float4(fa.x, fa.y, fb.x, fb.y);
    }
}

// ---- fallback (ws too small): R1-style monolithic kernel (fp32 tables) -----
__device__ __forceinline__ void gather_level_f32(
    float x0, float x1, float x2, float r,
    const float2* __restrict__ tbl, float& c0, float& c1)
{
    const float xn0 = (x0 + 1.0f) * 0.5f * r;
    const float xn1 = (x1 + 1.0f) * 0.5f * r;
    const float xn2 = (x2 + 1.0f) * 0.5f * r;
    const float f0 = floorf(xn0), f1 = floorf(xn1), f2 = floorf(xn2);
    const unsigned v0 = (unsigned)(int)f0;
    const unsigned v1 = (unsigned)(int)f1;
    const unsigned v2 = (unsigned)(int)f2;
    const float w0 = xn0 - f0, w1 = xn1 - f1, w2 = xn2 - f2;
    c0 = 0.f; c1 = 0.f;
    #pragma unroll
    for (int k = 0; k < 8; ++k) {
        const unsigned vx = v0 + ((k >> 2) & 1);
        const unsigned vy = v1 + ((k >> 1) & 1);
        const unsigned vz = v2 + (k & 1);
        unsigned h = (vx * 1u) ^ (vy * 2654435761u) ^ (vz * 805459861u);
        h &= TABLE_MASK;
        const float wgt = ((k & 4) ? w0 : 1.0f - w0) *
                          ((k & 2) ? w1 : 1.0f - w1) *
                          ((k & 1) ? w2 : 1.0f - w2);
        const float2 f = tbl[h];
        c0 += wgt * f.x;
        c1 += wgt * f.y;
    }
}

__global__ __launch_bounds__(256)
void mono_kernel(const float* __restrict__ x, const float* __restrict__ tables,
                 float* __restrict__ out, ResArr res)
{
    int idx = blockIdx.x * blockDim.x + threadIdx.x;
    if (idx >= N_POINTS * N_GRIDS) return;
    int b = idx >> 4, g = idx & 15;
    float x0 = x[b * 3], x1 = x[b * 3 + 1], x2 = x[b * 3 + 2];
    bool inbox = (x0 >= -1.f) & (x0 <= 1.f) & (x1 >= -1.f) & (x1 <= 1.f) &
                 (x2 >= -1.f) & (x2 <= 1.f);
    float c0 = 0.f, c1 = 0.f;
    if (inbox) {
        const float2* tbl = (const float2*)tables + ((size_t)g << LOG2_T);
        gather_level_f32(x0, x1, x2, res.r[g], tbl, c0, c1);
    }
    ((float2*)out)[(size_t)b * N_GRIDS + g] = make_float2(c0, c1);
}

extern "C" void kernel_launch(void* const* d_in, const int* in_sizes, int n_in,
                              void* d_out, int out_size, void* d_ws, size_t ws_size,
                              hipStream_t stream)
{
    const float* x      = (const float*)d_in[0];
    const float* tables = (const float*)d_in[1];
    float* out          = (float*)d_out;

    ResArr res;
    double pls = exp((log(2048.0) - log(16.0)) / 15.0);
    for (int i = 0; i < N_GRIDS; ++i)
        res.r[i] = (float)floor(16.0 * pow(pls, (double)i));

    // ws layout:
    // [counter 256B][hist 128KB][rank 4MB][xw 16MB][ws2 64MB][tb 33.6MB]
    const size_t off_hist = 256;
    const size_t off_rank = off_hist + (size_t)N_CELLS * 4;
    const size_t off_xw   = off_rank + (size_t)N_POINTS * 4;
    const size_t off_ws2  = off_xw + (size_t)N_POINTS * 16;
    const size_t off_tb   = off_ws2 + (size_t)N_GRIDS * N_POINTS * 4;
    const size_t ws_needed = off_tb + (size_t)N_ENTRIES * 4;

    if (ws_size < ws_needed) {
        int total = N_POINTS * N_GRIDS;
        mono_kernel<<<(total + 255) / 256, 256, 0, stream>>>(x, tables, out, res);
        return;
    }

    char* w = (char*)d_ws;
    unsigned* counter = (unsigned*)w;
    unsigned* hist    = (unsigned*)(w + off_hist);
    int*      rank    = (int*)(w + off_rank);
    float4*   xw      = (float4*)(w + off_xw);
    unsigned* ws2     = (unsigned*)(w + off_ws2);
    unsigned* tb      = (unsigned*)(w + off_tb);

    (void)hipMemsetAsync(w, 0, off_rank, stream);   // counter + hist
    hist_kernel<<<NBLOCKS, 256, 0, stream>>>(x, rank, hist, out);
    scan_kernel<<<1, 1024, 0, stream>>>(hist, counter);
    scatter_conv_kernel<<<CONV_BLOCKS + NBLOCKS, 256, 0, stream>>>(
        tables, tb, x, rank, xw, hist);
    fused_levels_kernel<<<FUSED_BLOCKS, 256, 0, stream>>>(xw, counter, tb,
                                                          ws2, res);
    tail_kernel<<<TAILB_BLOCKS, 256, 0, stream>>>(xw, counter, ws2, out);
}